// Round 6
// baseline (722.717 us; speedup 1.0000x reference)
//
#include <hip/hip_runtime.h>
#include <math.h>

namespace {

constexpr int T_ = 1024;
constexpr int HKV_ = 8;
constexpr int M_ = 8;
constexpr int D_ = 64;
constexpr int WIN_ = 128;
constexpr float SCALE_ = 0.125f;   // 1/sqrt(64)

constexpr int IB_ = 8;             // query rows per block (1 per wave)
constexpr int NKEY_ = 136;         // staged keys: [i0-127, i0+8]
constexpr int NTHREADS_ = 512;

using f4 = __attribute__((ext_vector_type(4))) float;

// 512 threads = 8 waves; 6 waves/EU * 4 EU = 24 waves/CU = 3 blocks/CU
// (LDS 43.5 KB also allows exactly 3). VGPR cap ~84.
__global__ __launch_bounds__(NTHREADS_, 6)
void attn_qk_softmax(const float* __restrict__ qg,
                     const float* __restrict__ kg,
                     const float* __restrict__ sinks,
                     float* __restrict__ outg)
{
    __shared__ float k_lds[NKEY_ * D_];       // XOR-swizzled key rows (34.0 KB)
    __shared__ float p_lds[IB_][2][136];      // pad-17 probs, dbuf per m (8.7 KB)

    const int tid  = threadIdx.x;
    const int wave = tid >> 6;
    const int lane = tid & 63;
    const int h    = blockIdx.x / (T_ / IB_);
    const int i0   = (blockIdx.x % (T_ / IB_)) * IB_;
    const int base = i0 - (WIN_ - 1);         // global j of staged key r=0

    const int i   = i0 + wave;
    const int jlo = (i >= WIN_ - 1) ? (i - (WIN_ - 1)) : 0;
    const int cnt = i - jlo + 1;              // 1..128 valid keys
    const int tlo = jlo >> 8;                 // first chunk touching the band
    const int thi = i >> 8;                   // last chunk touching the band

    // ---- EARLY zero stores: out-of-band 1KB chunks of all 8 m rows.
    // Depends only on (i, jlo): issue before any LDS work so the store
    // pipe drains while staging + fma run. Full-line f4 coverage.
    {
        const f4 z = {0.f, 0.f, 0.f, 0.f};
        float* orow0 = outg + (((size_t)h * M_ * T_ + i) * T_) + lane * 4;
        #pragma unroll
        for (int t = 0; t < 4; ++t) {
            if (t >= tlo && t <= thi) continue;       // band chunk: written later
            #pragma unroll
            for (int m = 0; m < M_; ++m)
                *reinterpret_cast<f4*>(orow0 + (size_t)m * T_ * T_ + t * 256) = z;
        }
    }

    // ---- stage K window into LDS (swizzled: c4 ^= ((r>>1)&7)<<2) ----
    for (int f = tid; f < NKEY_ * (D_ / 4); f += NTHREADS_) {
        const int r  = f >> 4;
        const int c4 = (f & 15) << 2;
        const int j  = base + r;
        f4 v = {0.f, 0.f, 0.f, 0.f};
        if ((unsigned)j < (unsigned)T_)
            v = *reinterpret_cast<const f4*>(kg + ((size_t)j * HKV_ + h) * D_ + c4);
        const int sw = c4 ^ (((r >> 1) & 7) << 2);
        *reinterpret_cast<f4*>(&k_lds[r * D_ + sw]) = v;
    }
    __syncthreads();

    const int rlo = jlo - base;               // rel idx of first valid key

    const int idx0 = 2 * lane;
    const int idx1 = idx0 + 1;
    const bool v0 = idx0 < cnt;
    const bool v1 = idx1 < cnt;
    int r0 = rlo + idx0; if (r0 > NKEY_ - 1) r0 = NKEY_ - 1;
    int r1 = rlo + idx1; if (r1 > NKEY_ - 1) r1 = NKEY_ - 1;

    float acc0[M_], acc1[M_];
    #pragma unroll
    for (int m = 0; m < M_; ++m) { acc0[m] = 0.f; acc1[m] = 0.f; }

    const float* k0p = &k_lds[r0 * D_];
    const float* k1p = &k_lds[r1 * D_];
    const int sw0 = ((r0 >> 1) & 7) << 2;
    const int sw1 = ((r1 >> 1) & 7) << 2;

    // q: wave-uniform broadcast reads straight from global (L1-resident 2KB row)
    const float* qp = qg + ((size_t)i * HKV_ + h) * (M_ * D_);

    #pragma unroll
    for (int c = 0; c < 16; ++c) {
        const int c4 = c << 2;
        const f4 kv0 = *reinterpret_cast<const f4*>(k0p + (c4 ^ sw0));
        const f4 kv1 = *reinterpret_cast<const f4*>(k1p + (c4 ^ sw1));
        #pragma unroll
        for (int m = 0; m < M_; ++m) {
            const f4 qv = *reinterpret_cast<const f4*>(qp + m * D_ + c4);
            acc0[m] = fmaf(qv.x, kv0.x, acc0[m]);
            acc0[m] = fmaf(qv.y, kv0.y, acc0[m]);
            acc0[m] = fmaf(qv.z, kv0.z, acc0[m]);
            acc0[m] = fmaf(qv.w, kv0.w, acc0[m]);
            acc1[m] = fmaf(qv.x, kv1.x, acc1[m]);
            acc1[m] = fmaf(qv.y, kv1.y, acc1[m]);
            acc1[m] = fmaf(qv.z, kv1.z, acc1[m]);
            acc1[m] = fmaf(qv.w, kv1.w, acc1[m]);
        }
    }

    // ---- per-m softmax (with sink) + band-chunk gather + store ----
    #pragma unroll
    for (int m = 0; m < M_; ++m) {
        float l0 = v0 ? acc0[m] * SCALE_ : -INFINITY;
        float l1 = v1 ? acc1[m] * SCALE_ : -INFINITY;
        float mx = fmaxf(l0, l1);
        #pragma unroll
        for (int s = 1; s < 64; s <<= 1)
            mx = fmaxf(mx, __shfl_xor(mx, s, 64));
        const float slog = sinks[h * M_ + m];
        mx = fmaxf(mx, slog);
        float p0 = __expf(l0 - mx);            // exp(-inf)=0 for masked keys
        float p1 = __expf(l1 - mx);
        float sum = p0 + p1;
        #pragma unroll
        for (int s = 1; s < 64; s <<= 1)
            sum += __shfl_xor(sum, s, 64);
        const float inv = 1.0f / (sum + __expf(slog - mx));
        p0 *= inv;
        p1 *= inv;

        float* pb = p_lds[wave][m & 1];        // double buffer
        pb[idx0 + (idx0 >> 4)] = p0;
        pb[idx1 + (idx1 >> 4)] = p1;
        asm volatile("s_waitcnt lgkmcnt(0)" ::: "memory");  // writes visible to wave

        float* orow = outg + (((size_t)(h * M_ + m) * T_ + i) * T_);
        for (int t = tlo; t <= thi; ++t) {     // 1-2 band chunks, wave-uniform
            const int j = t * 256 + lane * 4;
            f4 ov;
            #pragma unroll
            for (int u = 0; u < 4; ++u) {
                int idx = j + u - jlo;
                const bool in = (unsigned)idx < (unsigned)cnt;
                int ci = idx; if (ci < 0) ci = 0; if (ci > 127) ci = 127;
                const float val = pb[ci + (ci >> 4)];
                ov[u] = in ? val : 0.0f;
            }
            *reinterpret_cast<f4*>(orow + j) = ov;   // plain cached 1KB/wave store
        }
    }
}

} // namespace

extern "C" void kernel_launch(void* const* d_in, const int* in_sizes, int n_in,
                              void* d_out, int out_size, void* d_ws, size_t ws_size,
                              hipStream_t stream) {
    const float* q     = (const float*)d_in[0];
    const float* k     = (const float*)d_in[1];
    const float* sinks = (const float*)d_in[2];
    float* out         = (float*)d_out;

    dim3 grid(HKV_ * (T_ / IB_));   // 8 heads * 128 i-blocks = 1024 blocks
    attn_qk_softmax<<<grid, NTHREADS_, 0, stream>>>(q, k, sinks, out);
}

// Round 7
// 576.976 us; speedup vs baseline: 1.2526x; 1.2526x over previous
//
#include <hip/hip_runtime.h>
#include <math.h>

namespace {

constexpr int T_ = 1024;
constexpr int HKV_ = 8;
constexpr int M_ = 8;
constexpr int D_ = 64;
constexpr int WIN_ = 128;
constexpr float SCALE_ = 0.125f;   // 1/sqrt(64)

constexpr int IB_ = 8;             // query rows per block (1 per wave)
constexpr int NKEY_ = 136;         // staged keys: [i0-127, i0+8]
constexpr int NTHREADS_ = 512;

using f4 = __attribute__((ext_vector_type(4))) float;

__device__ inline float bperm(int byte_addr, int src) {
    return __int_as_float(__builtin_amdgcn_ds_bpermute(byte_addr, src));
}

// NO launch_bounds: VGPR must stay at natural ~64-80. Round 6 showed a VGPR
// cap (40) costs ~1GB of symmetric scratch spill traffic (722us vs 56us).
__global__ void attn_qk_softmax(const float* __restrict__ qg,
                                const float* __restrict__ kg,
                                const float* __restrict__ sinks,
                                float* __restrict__ outg)
{
    __shared__ float k_lds[NKEY_ * D_];       // XOR-swizzled key rows (34.0 KB)
    __shared__ float q_lds[IB_][M_ * D_];     // per-wave q rows (16.0 KB)

    const int tid  = threadIdx.x;
    const int wave = tid >> 6;
    const int lane = tid & 63;
    const int h    = blockIdx.x / (T_ / IB_);
    const int i0   = (blockIdx.x % (T_ / IB_)) * IB_;
    const int base = i0 - (WIN_ - 1);         // global j of staged key r=0

    const int i   = i0 + wave;
    const int jlo = (i >= WIN_ - 1) ? (i - (WIN_ - 1)) : 0;
    const int cnt = i - jlo + 1;              // 1..128 valid keys
    const int tlo = jlo >> 8;                 // first 256-float chunk in band
    const int thi = i >> 8;                   // last chunk in band (thi-tlo<=1)

    // ---- stage K window into LDS (swizzled: c4 ^= ((r>>1)&7)<<2) ----
    for (int f = tid; f < NKEY_ * (D_ / 4); f += NTHREADS_) {
        const int r  = f >> 4;
        const int c4 = (f & 15) << 2;
        const int j  = base + r;
        f4 v = {0.f, 0.f, 0.f, 0.f};
        if ((unsigned)j < (unsigned)T_)
            v = *reinterpret_cast<const f4*>(kg + ((size_t)j * HKV_ + h) * D_ + c4);
        const int sw = c4 ^ (((r >> 1) & 7) << 2);
        *reinterpret_cast<f4*>(&k_lds[r * D_ + sw]) = v;
    }
    // ---- stage this wave's q rows ----
    {
        const float* qp = qg + ((size_t)i * HKV_ + h) * (M_ * D_);
        const int off = lane * 4;
        *reinterpret_cast<f4*>(&q_lds[wave][off]) =
            *reinterpret_cast<const f4*>(qp + off);
        *reinterpret_cast<f4*>(&q_lds[wave][off + 256]) =
            *reinterpret_cast<const f4*>(qp + off + 256);
    }
    // ---- preload sinks into registers BEFORE any stores (SMEM path;
    // keeps the post-barrier region free of vmcnt-counted loads) ----
    float slogv[M_];
    #pragma unroll
    for (int m = 0; m < M_; ++m) slogv[m] = sinks[h * M_ + m];

    __syncthreads();

    // ---- EARLY zero stores: out-of-band 1KB chunks of all 8 m rows.
    // Post-barrier there are NO global loads, so nothing ever waits on the
    // store queue: these drain under the fma/softmax compute below.
    {
        const f4 z = {0.f, 0.f, 0.f, 0.f};
        float* o0 = outg + (((size_t)h * M_ * T_ + i) * T_) + lane * 4;
        #pragma unroll
        for (int t = 0; t < 4; ++t) {
            if (t >= tlo && t <= thi) continue;    // band chunk: written later
            #pragma unroll
            for (int m = 0; m < M_; ++m)
                *reinterpret_cast<f4*>(o0 + (size_t)m * T_ * T_ + t * 256) = z;
        }
    }

    const int rlo = jlo - base;               // rel idx of first valid key
    const int idx0 = 2 * lane;
    const int idx1 = idx0 + 1;
    const bool v0 = idx0 < cnt;
    const bool v1 = idx1 < cnt;
    int r0 = rlo + idx0; if (r0 > NKEY_ - 1) r0 = NKEY_ - 1;
    int r1 = rlo + idx1; if (r1 > NKEY_ - 1) r1 = NKEY_ - 1;

    float acc0[M_], acc1[M_];
    #pragma unroll
    for (int m = 0; m < M_; ++m) { acc0[m] = 0.f; acc1[m] = 0.f; }

    const float* k0p = &k_lds[r0 * D_];
    const float* k1p = &k_lds[r1 * D_];
    const int sw0 = ((r0 >> 1) & 7) << 2;
    const int sw1 = ((r1 >> 1) & 7) << 2;

    #pragma unroll
    for (int c = 0; c < 16; ++c) {
        const int c4 = c << 2;
        const f4 kv0 = *reinterpret_cast<const f4*>(k0p + (c4 ^ sw0));
        const f4 kv1 = *reinterpret_cast<const f4*>(k1p + (c4 ^ sw1));
        #pragma unroll
        for (int m = 0; m < M_; ++m) {
            const f4 qv = *reinterpret_cast<const f4*>(&q_lds[wave][m * D_ + c4]);
            acc0[m] = fmaf(qv.x, kv0.x, acc0[m]);
            acc0[m] = fmaf(qv.y, kv0.y, acc0[m]);
            acc0[m] = fmaf(qv.z, kv0.z, acc0[m]);
            acc0[m] = fmaf(qv.w, kv0.w, acc0[m]);
            acc1[m] = fmaf(qv.x, kv1.x, acc1[m]);
            acc1[m] = fmaf(qv.y, kv1.y, acc1[m]);
            acc1[m] = fmaf(qv.z, kv1.z, acc1[m]);
            acc1[m] = fmaf(qv.w, kv1.w, acc1[m]);
        }
    }

    // ---- per-m softmax (with sink) + bpermute-shift band store ----
    #pragma unroll
    for (int m = 0; m < M_; ++m) {
        float l0 = v0 ? acc0[m] * SCALE_ : -INFINITY;
        float l1 = v1 ? acc1[m] * SCALE_ : -INFINITY;
        float mx = fmaxf(l0, l1);
        #pragma unroll
        for (int s = 1; s < 64; s <<= 1)
            mx = fmaxf(mx, __shfl_xor(mx, s, 64));
        mx = fmaxf(mx, slogv[m]);
        float p0 = __expf(l0 - mx);            // exp(-inf)=0 for masked keys
        float p1 = __expf(l1 - mx);
        float sum = p0 + p1;
        #pragma unroll
        for (int s = 1; s < 64; s <<= 1)
            sum += __shfl_xor(sum, s, 64);
        const float inv = 1.0f / (sum + __expf(slogv[m] - mx));
        p0 *= inv;                              // = prob of key idx0 (0 if invalid)
        p1 *= inv;                              // = prob of key idx1

        const int iP0 = __float_as_int(p0);
        const int iP1 = __float_as_int(p1);
        float* orow = outg + (((size_t)(h * M_ + m) * T_ + i) * T_);

        for (int t = tlo; t <= thi; ++t) {     // 1-2 band chunks, wave-uniform
            // lane owns row floats j..j+3; key index b = j - jlo.
            // key b lives in lane b>>1, slot b&1; parity of b is wave-uniform.
            const int b  = t * 256 + lane * 4 - jlo;
            const int sb = (b >> 1) << 2;      // byte addr of source lane
            const float A0 = bperm(sb,     iP0);
            const float A1 = bperm(sb,     iP1);
            const float B0 = bperm(sb + 4, iP0);
            const float B1 = bperm(sb + 4, iP1);
            f4 ov;
            if ((b & 1) == 0) {                // wave-uniform branch
                ov = (f4){A0, A1, B0, B1};
            } else {
                const float C0 = bperm(sb + 8, iP0);
                ov = (f4){A1, B0, B1, C0};
            }
            #pragma unroll
            for (int u = 0; u < 4; ++u)
                ov[u] = ((unsigned)(b + u) < (unsigned)cnt) ? ov[u] : 0.f;
            *reinterpret_cast<f4*>(orow + t * 256 + lane * 4) = ov;  // 1KB/wave
        }
    }
}

} // namespace

extern "C" void kernel_launch(void* const* d_in, const int* in_sizes, int n_in,
                              void* d_out, int out_size, void* d_ws, size_t ws_size,
                              hipStream_t stream) {
    const float* q     = (const float*)d_in[0];
    const float* k     = (const float*)d_in[1];
    const float* sinks = (const float*)d_in[2];
    float* out         = (float*)d_out;

    dim3 grid(HKV_ * (T_ / IB_));   // 8 heads * 128 i-blocks = 1024 blocks
    attn_qk_softmax<<<grid, NTHREADS_, 0, stream>>>(q, k, sinks, out);
}

// Round 8
// 72.262 us; speedup vs baseline: 10.0014x; 7.9845x over previous
//
#include <hip/hip_runtime.h>
#include <math.h>

namespace {

constexpr int T_ = 1024;
constexpr int HKV_ = 8;
constexpr int M_ = 8;
constexpr int D_ = 64;
constexpr int WIN_ = 128;
constexpr float SCALE_ = 0.125f;   // 1/sqrt(64)

constexpr int IB_ = 8;             // query rows per block (1 per wave)
constexpr int NKEY_ = 136;         // staged keys: [i0-127, i0+8]
constexpr int NTHREADS_ = 512;

using f4 = __attribute__((ext_vector_type(4))) float;

// Round-4 structure (proven 56.3us, clean counters) with exactly ONE change:
// q_lds removed; q is read via a readfirstlane-uniform pointer so the
// compiler emits scalar s_load (constant cache), cutting LDS 59.9->43.5 KB
// (2 -> 3 blocks/CU). No launch_bounds (R6: VGPR cap => ~1GB spill tax).
__global__ void attn_qk_softmax(const float* __restrict__ qg,
                                const float* __restrict__ kg,
                                const float* __restrict__ sinks,
                                float* __restrict__ outg)
{
    __shared__ float k_lds[NKEY_ * D_];       // XOR-swizzled key rows (34.8 KB)
    __shared__ float p_lds[IB_][2][136];      // pad-17 probs, dbuf per m (8.7 KB)

    const int tid  = threadIdx.x;
    const int wave = tid >> 6;
    const int lane = tid & 63;
    const int h    = blockIdx.x / (T_ / IB_);
    const int i0   = (blockIdx.x % (T_ / IB_)) * IB_;
    const int base = i0 - (WIN_ - 1);         // global j of staged key r=0

    // ---- stage K window into LDS (swizzled: c4 ^= ((r>>1)&7)<<2) ----
    for (int f = tid; f < NKEY_ * (D_ / 4); f += NTHREADS_) {
        const int r  = f >> 4;
        const int c4 = (f & 15) << 2;
        const int j  = base + r;
        f4 v = {0.f, 0.f, 0.f, 0.f};
        if ((unsigned)j < (unsigned)T_)
            v = *reinterpret_cast<const f4*>(kg + ((size_t)j * HKV_ + h) * D_ + c4);
        const int sw = c4 ^ (((r >> 1) & 7) << 2);
        *reinterpret_cast<f4*>(&k_lds[r * D_ + sw]) = v;
    }
    __syncthreads();

    const int i   = i0 + wave;
    const int jlo = (i >= WIN_ - 1) ? (i - (WIN_ - 1)) : 0;
    const int cnt = i - jlo + 1;              // 1..128 valid keys
    const int rlo = jlo - base;               // rel idx of first valid key

    // q: wave-uniform pointer, forced into an SGPR -> scalar-cache s_loads
    const float* qp = qg +
        (size_t)__builtin_amdgcn_readfirstlane((i * HKV_ + h) * (M_ * D_));

    const int idx0 = 2 * lane;
    const int idx1 = idx0 + 1;
    const bool v0 = idx0 < cnt;
    const bool v1 = idx1 < cnt;
    int r0 = rlo + idx0; if (r0 > NKEY_ - 1) r0 = NKEY_ - 1;
    int r1 = rlo + idx1; if (r1 > NKEY_ - 1) r1 = NKEY_ - 1;

    float acc0[M_], acc1[M_];
    #pragma unroll
    for (int m = 0; m < M_; ++m) { acc0[m] = 0.f; acc1[m] = 0.f; }

    const float* k0p = &k_lds[r0 * D_];
    const float* k1p = &k_lds[r1 * D_];
    const int sw0 = ((r0 >> 1) & 7) << 2;
    const int sw1 = ((r1 >> 1) & 7) << 2;

    #pragma unroll
    for (int c = 0; c < 16; ++c) {
        const int c4 = c << 2;
        const f4 kv0 = *reinterpret_cast<const f4*>(k0p + (c4 ^ sw0));
        const f4 kv1 = *reinterpret_cast<const f4*>(k1p + (c4 ^ sw1));
        #pragma unroll
        for (int m = 0; m < M_; ++m) {
            const f4 qv = *reinterpret_cast<const f4*>(qp + m * D_ + c4);
            acc0[m] = fmaf(qv.x, kv0.x, acc0[m]);
            acc0[m] = fmaf(qv.y, kv0.y, acc0[m]);
            acc0[m] = fmaf(qv.z, kv0.z, acc0[m]);
            acc0[m] = fmaf(qv.w, kv0.w, acc0[m]);
            acc1[m] = fmaf(qv.x, kv1.x, acc1[m]);
            acc1[m] = fmaf(qv.y, kv1.y, acc1[m]);
            acc1[m] = fmaf(qv.z, kv1.z, acc1[m]);
            acc1[m] = fmaf(qv.w, kv1.w, acc1[m]);
        }
    }

    // ---- per-m softmax (with sink) + full-row PLAIN contiguous store ----
    #pragma unroll
    for (int m = 0; m < M_; ++m) {
        float l0 = v0 ? acc0[m] * SCALE_ : -INFINITY;
        float l1 = v1 ? acc1[m] * SCALE_ : -INFINITY;
        float mx = fmaxf(l0, l1);
        #pragma unroll
        for (int s = 1; s < 64; s <<= 1)
            mx = fmaxf(mx, __shfl_xor(mx, s, 64));
        const float slog = sinks[h * M_ + m];
        mx = fmaxf(mx, slog);
        float p0 = __expf(l0 - mx);            // exp(-inf)=0 for masked keys
        float p1 = __expf(l1 - mx);
        float sum = p0 + p1;
        #pragma unroll
        for (int s = 1; s < 64; s <<= 1)
            sum += __shfl_xor(sum, s, 64);
        const float inv = 1.0f / (sum + __expf(slog - mx));
        p0 *= inv;
        p1 *= inv;

        float* pb = p_lds[wave][m & 1];        // double buffer
        pb[idx0 + (idx0 >> 4)] = p0;
        pb[idx1 + (idx1 >> 4)] = p1;
        asm volatile("s_waitcnt lgkmcnt(0)" ::: "memory");  // writes visible to wave

        // Full 4 KB row, 4 plain f4 stores per lane; each instruction covers
        // 1 KB contiguous = 8 full 128B lines sourced entirely from this wave.
        float* orow = outg + (((size_t)(h * M_ + m) * T_ + i) * T_);
        #pragma unroll
        for (int t = 0; t < 4; ++t) {
            const int j = t * 256 + lane * 4;  // float index in row
            f4 ov;
            #pragma unroll
            for (int u = 0; u < 4; ++u) {
                int idx = j + u - jlo;
                const bool in = (unsigned)idx < (unsigned)cnt;
                int ci = idx; if (ci < 0) ci = 0; if (ci > 127) ci = 127;
                const float val = pb[ci + (ci >> 4)];
                ov[u] = in ? val : 0.0f;
            }
            *reinterpret_cast<f4*>(orow + j) = ov;   // plain cached store
        }
    }
}

} // namespace

extern "C" void kernel_launch(void* const* d_in, const int* in_sizes, int n_in,
                              void* d_out, int out_size, void* d_ws, size_t ws_size,
                              hipStream_t stream) {
    const float* q     = (const float*)d_in[0];
    const float* k     = (const float*)d_in[1];
    const float* sinks = (const float*)d_in[2];
    float* out         = (float*)d_out;

    dim3 grid(HKV_ * (T_ / IB_));   // 8 heads * 128 i-blocks = 1024 blocks
    attn_qk_softmax<<<grid, NTHREADS_, 0, stream>>>(q, k, sinks, out);
}

// Round 9
// 55.490 us; speedup vs baseline: 13.0243x; 1.3022x over previous
//
#include <hip/hip_runtime.h>
#include <math.h>

namespace {

constexpr int T_ = 1024;
constexpr int HKV_ = 8;
constexpr int M_ = 8;
constexpr int D_ = 64;
constexpr int WIN_ = 128;
constexpr float SCALE_ = 0.125f;   // 1/sqrt(64)

constexpr int IB_ = 8;             // query rows per block (1 per wave)
constexpr int NKEY_ = 136;         // staged keys: [i0-127, i0+8]
constexpr int NTHREADS_ = 512;

using f4 = __attribute__((ext_vector_type(4))) float;

// float -> bf16 (round-nearest-even), packed pair
__device__ inline unsigned bf16rne_pack(float x, float y) {
    unsigned bx = __float_as_uint(x);
    unsigned by = __float_as_uint(y);
    bx = (bx + 0x7FFFu + ((bx >> 16) & 1u)) >> 16;
    by = (by + 0x7FFFu + ((by >> 16) & 1u)) >> 16;
    return bx | (by << 16);
}

// Round-4 structure (proven 56.3us, clean counters) with exactly ONE change:
// q_lds stored as bf16 (RNE) instead of f32 -> LDS 59.5 -> 50.5 KB
// -> 3 blocks/CU instead of 2. q reads remain wave-uniform LDS broadcasts
// (NO global loads in the post-barrier region: R8 showed vmcnt sharing
// between loads and stores costs +16us). No launch_bounds (R6: VGPR cap
// => ~1GB symmetric spill tax).
__global__ void attn_qk_softmax(const float* __restrict__ qg,
                                const float* __restrict__ kg,
                                const float* __restrict__ sinks,
                                float* __restrict__ outg)
{
    __shared__ float    k_lds[NKEY_ * D_];     // XOR-swizzled key rows (34.8 KB)
    __shared__ unsigned q_lds[IB_][M_ * D_ / 2]; // bf16-packed q rows (8 KB)
    __shared__ float    p_lds[IB_][2][136];    // pad-17 probs, dbuf (8.7 KB)

    const int tid  = threadIdx.x;
    const int wave = tid >> 6;
    const int lane = tid & 63;
    const int h    = blockIdx.x / (T_ / IB_);
    const int i0   = (blockIdx.x % (T_ / IB_)) * IB_;
    const int base = i0 - (WIN_ - 1);          // global j of staged key r=0

    // ---- stage K window into LDS (swizzled: c4 ^= ((r>>1)&7)<<2) ----
    for (int f = tid; f < NKEY_ * (D_ / 4); f += NTHREADS_) {
        const int r  = f >> 4;
        const int c4 = (f & 15) << 2;
        const int j  = base + r;
        f4 v = {0.f, 0.f, 0.f, 0.f};
        if ((unsigned)j < (unsigned)T_)
            v = *reinterpret_cast<const f4*>(kg + ((size_t)j * HKV_ + h) * D_ + c4);
        const int sw = c4 ^ (((r >> 1) & 7) << 2);
        *reinterpret_cast<f4*>(&k_lds[r * D_ + sw]) = v;
    }
    // ---- stage this wave's q rows as packed bf16 ----
    {
        const int i = i0 + wave;
        const float* qp = qg + ((size_t)i * HKV_ + h) * (M_ * D_);
        const int off = lane * 4;              // float index within the row
        const f4 a = *reinterpret_cast<const f4*>(qp + off);
        const f4 b = *reinterpret_cast<const f4*>(qp + off + 256);
        uint2 pa, pb2;
        pa.x  = bf16rne_pack(a.x, a.y);
        pa.y  = bf16rne_pack(a.z, a.w);
        pb2.x = bf16rne_pack(b.x, b.y);
        pb2.y = bf16rne_pack(b.z, b.w);
        *reinterpret_cast<uint2*>(&q_lds[wave][off / 2])         = pa;
        *reinterpret_cast<uint2*>(&q_lds[wave][(off + 256) / 2]) = pb2;
    }
    __syncthreads();

    const int i   = i0 + wave;
    const int jlo = (i >= WIN_ - 1) ? (i - (WIN_ - 1)) : 0;
    const int cnt = i - jlo + 1;               // 1..128 valid keys
    const int rlo = jlo - base;                // rel idx of first valid key

    const int idx0 = 2 * lane;
    const int idx1 = idx0 + 1;
    const bool v0 = idx0 < cnt;
    const bool v1 = idx1 < cnt;
    int r0 = rlo + idx0; if (r0 > NKEY_ - 1) r0 = NKEY_ - 1;
    int r1 = rlo + idx1; if (r1 > NKEY_ - 1) r1 = NKEY_ - 1;

    float acc0[M_], acc1[M_];
    #pragma unroll
    for (int m = 0; m < M_; ++m) { acc0[m] = 0.f; acc1[m] = 0.f; }

    const float* k0p = &k_lds[r0 * D_];
    const float* k1p = &k_lds[r1 * D_];
    const int sw0 = ((r0 >> 1) & 7) << 2;
    const int sw1 = ((r1 >> 1) & 7) << 2;

    #pragma unroll
    for (int c = 0; c < 16; ++c) {
        const int c4 = c << 2;
        const f4 kv0 = *reinterpret_cast<const f4*>(k0p + (c4 ^ sw0));
        const f4 kv1 = *reinterpret_cast<const f4*>(k1p + (c4 ^ sw1));
        #pragma unroll
        for (int m = 0; m < M_; ++m) {
            // wave-uniform broadcast read of 4 bf16-packed q values (8B)
            const uint2 qw = *reinterpret_cast<const uint2*>(
                &q_lds[wave][(m * D_ + c4) / 2]);
            const float q0 = __uint_as_float(qw.x << 16);
            const float q1 = __uint_as_float(qw.x & 0xFFFF0000u);
            const float q2 = __uint_as_float(qw.y << 16);
            const float q3 = __uint_as_float(qw.y & 0xFFFF0000u);
            acc0[m] = fmaf(q0, kv0.x, acc0[m]);
            acc0[m] = fmaf(q1, kv0.y, acc0[m]);
            acc0[m] = fmaf(q2, kv0.z, acc0[m]);
            acc0[m] = fmaf(q3, kv0.w, acc0[m]);
            acc1[m] = fmaf(q0, kv1.x, acc1[m]);
            acc1[m] = fmaf(q1, kv1.y, acc1[m]);
            acc1[m] = fmaf(q2, kv1.z, acc1[m]);
            acc1[m] = fmaf(q3, kv1.w, acc1[m]);
        }
    }

    // ---- per-m softmax (with sink) + full-row PLAIN contiguous store ----
    #pragma unroll
    for (int m = 0; m < M_; ++m) {
        float l0 = v0 ? acc0[m] * SCALE_ : -INFINITY;
        float l1 = v1 ? acc1[m] * SCALE_ : -INFINITY;
        float mx = fmaxf(l0, l1);
        #pragma unroll
        for (int s = 1; s < 64; s <<= 1)
            mx = fmaxf(mx, __shfl_xor(mx, s, 64));
        const float slog = sinks[h * M_ + m];
        mx = fmaxf(mx, slog);
        float p0 = __expf(l0 - mx);            // exp(-inf)=0 for masked keys
        float p1 = __expf(l1 - mx);
        float sum = p0 + p1;
        #pragma unroll
        for (int s = 1; s < 64; s <<= 1)
            sum += __shfl_xor(sum, s, 64);
        const float inv = 1.0f / (sum + __expf(slog - mx));
        p0 *= inv;
        p1 *= inv;

        float* pb = p_lds[wave][m & 1];        // double buffer
        pb[idx0 + (idx0 >> 4)] = p0;
        pb[idx1 + (idx1 >> 4)] = p1;
        asm volatile("s_waitcnt lgkmcnt(0)" ::: "memory");  // writes visible to wave

        // Full 4 KB row, 4 plain f4 stores per lane; each instruction covers
        // 1 KB contiguous = 8 full 128B lines sourced entirely from this wave.
        float* orow = outg + (((size_t)(h * M_ + m) * T_ + i) * T_);
        #pragma unroll
        for (int t = 0; t < 4; ++t) {
            const int j = t * 256 + lane * 4;  // float index in row
            f4 ov;
            #pragma unroll
            for (int u = 0; u < 4; ++u) {
                int idx = j + u - jlo;
                const bool in = (unsigned)idx < (unsigned)cnt;
                int ci = idx; if (ci < 0) ci = 0; if (ci > 127) ci = 127;
                const float val = pb[ci + (ci >> 4)];
                ov[u] = in ? val : 0.0f;
            }
            *reinterpret_cast<f4*>(orow + j) = ov;   // plain cached store
        }
    }
}

} // namespace

extern "C" void kernel_launch(void* const* d_in, const int* in_sizes, int n_in,
                              void* d_out, int out_size, void* d_ws, size_t ws_size,
                              hipStream_t stream) {
    const float* q     = (const float*)d_in[0];
    const float* k     = (const float*)d_in[1];
    const float* sinks = (const float*)d_in[2];
    float* out         = (float*)d_out;

    dim3 grid(HKV_ * (T_ / IB_));   // 8 heads * 128 i-blocks = 1024 blocks
    attn_qk_softmax<<<grid, NTHREADS_, 0, stream>>>(q, k, sinks, out);
}